// Round 8
// baseline (1434.798 us; speedup 1.0000x reference)
//
#include <hip/hip_runtime.h>
#include <hip/hip_fp16.h>

typedef _Float16 half8  __attribute__((ext_vector_type(8)));
typedef _Float16 half2v __attribute__((ext_vector_type(2)));
typedef float    f32x4  __attribute__((ext_vector_type(4)));

#define MFMA16(af, bf, cf) __builtin_amdgcn_mfma_f32_16x16x32_f16((af), (bf), (cf), 0, 0, 0)

// ---------------- workspace layout (halves) ----------------
#define WS_WL1   0                        // [k1;rk1] packed [nt0..31][kt0..7][512] = 131072
#define WS_RK0   131072                   // rk0 packed [nt][kt0..3][512] = 65536
#define WS_W0    (131072 + 65536)         // W0' = W_in@k0 packed [nt][kt0..2][512] = 49152
#define WS_WOUTT (WS_W0 + 49152)          // Wout^T packed [m0..1][kt0..3][512] = 4096
#define WS_B0    (WS_WOUTT + 4096)        // float b0'[512] (1024 halves)
#define WS_CB    (WS_B0 + 1024)           // float cb[512] = bout@W0a (1024 halves)

// ---------------- LDS layout (halves) ----------------
#define PA0  72                            // 64 x cols + 8 pad
#define PH   136                           // 128 cols + 8 pad
#define PRES 40                            // 32 res cols + 8 pad (16B-aligned rows)
#define L_A0X  0                           // 2 x [16][72] = 2304
#define L_H0   2304                        // 2 x [16][136] = 4352
#define L_H1   (L_H0 + 4352)               // 6656
#define L_WOUT (L_H1 + 4352)               // 11008: [2m][4kt][512] = 4096
#define L_RES  (L_WOUT + 4096)             // 15104: 8 waves x [16][40] = 5120
#define L_K1   (L_RES + 5120)              // 20224: k1 kt0..2 [nt][3kt][512] = 49152
#define L_TOT  (L_K1 + 49152)              // 69376 halves = 138752 B

__device__ __forceinline__ float sigm(float x) {
    return __builtin_amdgcn_rcpf(1.0f + __builtin_amdgcn_exp2f(-1.442695041f * x));
}
__device__ __forceinline__ float tanh_(float x) {
    return 1.0f - 2.0f * __builtin_amdgcn_rcpf(__builtin_amdgcn_exp2f(2.885390082f * x) + 1.0f);
}
// raw barrier: drain LDS only; global loads/stores stay in flight.
__device__ __forceinline__ void bar() {
    asm volatile("s_waitcnt lgkmcnt(0)" ::: "memory");
    __builtin_amdgcn_s_barrier();
    asm volatile("" ::: "memory");
}

// ---- pack kernels ----
__global__ void pack_layer_k(const float* __restrict__ kk, const float* __restrict__ rk,
                             _Float16* __restrict__ dst)
{
    int idx  = blockIdx.x * 256 + threadIdx.x;
    int j    = idx & 7;
    int lane = (idx >> 3) & 63;
    int fk   = idx >> 9;
    int kt   = fk & 7;
    int nt   = fk >> 3;
    int w = nt >> 3, ln = nt & 7, g = ln >> 1, hh = ln & 1;
    int col = g*128 + w*32 + hh*16 + (lane & 15);
    int row = kt*32 + (lane >> 4)*8 + j;
    float v = (row < 128) ? kk[row*512 + col] : rk[(row - 128)*512 + col];
    dst[idx] = (_Float16)v;
}

__global__ void pack_rk(const float* __restrict__ rk, _Float16* __restrict__ dst)
{
    int idx = blockIdx.x * 256 + threadIdx.x;
    int j = idx & 7, lane = (idx >> 3) & 63, fk = idx >> 9;
    int kt = fk & 3, nt = fk >> 2;
    int w = nt >> 3, ln = nt & 7, g = ln >> 1, hh = ln & 1;
    int col = g*128 + w*32 + hh*16 + (lane & 15);
    int row = kt*32 + (lane >> 4)*8 + j;
    dst[idx] = (_Float16)rk[row*512 + col];
}

__global__ void pack_w0(const float* __restrict__ W_in, const float* __restrict__ k0,
                        _Float16* __restrict__ dst)
{
    int idx = blockIdx.x * 256 + threadIdx.x;
    int j = idx & 7, lane = (idx >> 3) & 63, fk = idx >> 9;
    int kt = fk % 3, nt = fk / 3;
    int w = nt >> 3, ln = nt & 7, g = ln >> 1, hh = ln & 1;
    int col = g*128 + w*32 + hh*16 + (lane & 15);
    int row = kt*32 + (lane >> 4)*8 + j;   // rows 0..63 = x, 64..95 = acc
    float s = 0.f;
    #pragma unroll 4
    for (int k = 0; k < 128; ++k) s += W_in[row*128 + k] * k0[k*512 + col];
    dst[idx] = (_Float16)s;
}

__global__ void pack_b0(const float* __restrict__ b_in, const float* __restrict__ k0,
                        const float* __restrict__ bb0, float* __restrict__ b0p)
{
    int col = blockIdx.x * 256 + threadIdx.x;
    float s = bb0[col];
    #pragma unroll 4
    for (int k = 0; k < 128; ++k) s += b_in[k] * k0[k*512 + col];
    b0p[col] = s;
}

// Wout^T as A-frags: dst[(m*4+kt)*512 + lane*8 + j] = Wout[kt*32+(lane>>4)*8+j][m*16+(lane&15)]
__global__ void pack_woutT(const float* __restrict__ W_out, _Float16* __restrict__ dst)
{
    int idx = blockIdx.x * 256 + threadIdx.x;   // < 4096
    int j = idx & 7, lane = (idx >> 3) & 63, fk = idx >> 9;
    int kt = fk & 3, m = fk >> 2;
    int row = kt*32 + (lane >> 4)*8 + j;
    int col = m*16 + (lane & 15);
    dst[idx] = (_Float16)W_out[row*32 + col];
}

// cb[zcol] = sum_c bout[c] * W0a[c][zcol],  W0a = W_in rows 64..95 @ k0
__global__ void pack_cb(const float* __restrict__ W_in, const float* __restrict__ k0,
                        const float* __restrict__ bout, float* __restrict__ cbp)
{
    int zc = blockIdx.x * 256 + threadIdx.x;    // < 512
    float s = 0.f;
    for (int c = 0; c < 32; ++c) {
        float wv = 0.f;
        #pragma unroll 4
        for (int k = 0; k < 128; ++k) wv += W_in[(64 + c)*128 + k] * k0[k*512 + zc];
        s += bout[c] * wv;
    }
    cbp[zc] = s;
}

// 8 waves (2/SIMD). Wave W=(w4,hh) owns hidden cols w4*32+hh*16+[0,16) of every
// gate. 2 barriers/step. acc lives in registers (A-frag layout); every wave
// computes GEMM4 redundantly and transposes res wave-locally (no barrier).
// z-init = b0' + t*cb accounts for bout folded out of the register acc.
__global__ __launch_bounds__(512, 2)
void acclstm_main(const float* __restrict__ xin,
                  const _Float16* __restrict__ wl1p, const _Float16* __restrict__ rk0p,
                  const _Float16* __restrict__ w0p,  const _Float16* __restrict__ woutTp,
                  const float* __restrict__ b0p, const float* __restrict__ cbp,
                  const float* __restrict__ bb1, const float* __restrict__ bout,
                  float* __restrict__ out)
{
    __shared__ __align__(16) _Float16 lds[L_TOT];
    const int tid  = threadIdx.x;
    const int W    = tid >> 6;
    const int lane = tid & 63;
    const int w4   = W & 3;
    const int hh   = W >> 2;
    const int l15  = lane & 15;
    const int lg   = lane >> 4;
    const int b0   = blockIdx.x << 4;
    const int colw = w4*32 + hh*16 + l15;
    const int nt0 = w4*8 + 0 + hh, nt1 = w4*8 + 2 + hh, nt2 = w4*8 + 4 + hh, nt3 = w4*8 + 6 + hh;

    // ---- LDS fills ----
    for (int i = tid; i < 6144; i += 512) {       // k1 kt0..2
        int h = i << 3, nt = h / 1536, rem = h % 1536;
        *reinterpret_cast<uint4*>(&lds[L_K1 + h]) =
            *reinterpret_cast<const uint4*>(&wl1p[nt*4096 + rem]);
    }
    if (tid < 512)
        *reinterpret_cast<uint4*>(&lds[L_WOUT + (tid << 3)]) =
            *reinterpret_cast<const uint4*>(&woutTp[tid << 3]);
    {   // zero H0[0] and H1[0] completely (272 uint4 each)
        uint4 z; z.x = z.y = z.z = z.w = 0u;
        if (tid < 272) {
            *reinterpret_cast<uint4*>(&lds[L_H0 + (tid << 3)]) = z;
            *reinterpret_cast<uint4*>(&lds[L_H1 + (tid << 3)]) = z;
        }
    }

    // ---- persistent weight fragments (w0-x part is STREAMED per step) ----
    half8 w0a[4], rk0r[4][4], rk1r[4][4], k1r[4];
    {
        const int nts[4] = {nt0, nt1, nt2, nt3};
        #pragma unroll
        for (int g = 0; g < 4; ++g) {
            const int nt = nts[g];
            w0a[g] = *reinterpret_cast<const half8*>(&w0p[(nt*3 + 2)*512 + lane*8]);
            #pragma unroll
            for (int kt = 0; kt < 4; ++kt)
                rk0r[g][kt] = *reinterpret_cast<const half8*>(&rk0p[(nt*4 + kt)*512 + lane*8]);
            #pragma unroll
            for (int kt = 0; kt < 4; ++kt)
                rk1r[g][kt] = *reinterpret_cast<const half8*>(&wl1p[(nt*8 + 4 + kt)*512 + lane*8]);
            k1r[g] = *reinterpret_cast<const half8*>(&wl1p[(nt*8 + 3)*512 + lane*8]);
        }
    }
    float b0v[4], cbv[4], b1v[4];
    #pragma unroll
    for (int g = 0; g < 4; ++g) {
        b0v[g] = b0p[g*128 + colw];
        cbv[g] = cbp[g*128 + colw];
        b1v[g] = bb1[g*128 + colw];
    }
    float boutv4[4];
    #pragma unroll
    for (int r = 0; r < 4; ++r)
        boutv4[r] = bout[(W < 2 ? W : 0)*16 + lg*4 + r];

    f32x4 c0 = {0.f,0.f,0.f,0.f}, c1 = {0.f,0.f,0.f,0.f};
    float accv[8];                      // acc (bias-free) in A-frag layout
    #pragma unroll
    for (int j = 0; j < 8; ++j) accv[j] = 0.f;

    const int xrow2 = tid >> 5, xc2 = (tid & 31) << 1;
    const int resw  = L_RES + W*640 + l15*PRES;   // wave-private transpose buffer

    __syncthreads();
    // stage x(0) -> A0X[0]; xr = x(1)
    float2 xr = *reinterpret_cast<const float2*>(&xin[(size_t)(b0 + xrow2)*16384 + xc2]);
    {
        half2v xh = { (_Float16)xr.x, (_Float16)xr.y };
        *reinterpret_cast<half2v*>(&lds[L_A0X + xrow2*PA0 + xc2]) = xh;
    }
    xr = *reinterpret_cast<const float2*>(&xin[(size_t)(b0 + xrow2)*16384 + 64 + xc2]);
    __syncthreads();

    auto step = [&](auto PARc, int t) {
        constexpr int PAR = decltype(PARc)::value;
        constexpr int A0r = L_A0X + PAR*1152, A0w = L_A0X + (PAR^1)*1152;
        constexpr int H0r = L_H0 + PAR*2176,  H0w = L_H0 + (PAR^1)*2176;
        constexpr int H1r = L_H1 + PAR*2176,  H1w = L_H1 + (PAR^1)*2176;

        // ======== seg1: z0 = (b0'+t*cb) + x@W0x + acc@W0a + h0_prev@rk0 ========
        {
            // stream w0-x frags (fixed addresses -> L1-resident after step 0)
            half8 wx[4][2];
            #pragma unroll
            for (int g = 0; g < 4; ++g) {
                const int nt = (g==0)?nt0:(g==1)?nt1:(g==2)?nt2:nt3;
                wx[g][0] = *reinterpret_cast<const half8*>(&w0p[(nt*3 + 0)*512 + lane*8]);
                wx[g][1] = *reinterpret_cast<const half8*>(&w0p[(nt*3 + 1)*512 + lane*8]);
            }
            const float tf = (float)t;
            f32x4 z0 = {b0v[0]+tf*cbv[0], b0v[0]+tf*cbv[0], b0v[0]+tf*cbv[0], b0v[0]+tf*cbv[0]};
            f32x4 z1 = {b0v[1]+tf*cbv[1], b0v[1]+tf*cbv[1], b0v[1]+tf*cbv[1], b0v[1]+tf*cbv[1]};
            f32x4 z2 = {b0v[2]+tf*cbv[2], b0v[2]+tf*cbv[2], b0v[2]+tf*cbv[2], b0v[2]+tf*cbv[2]};
            f32x4 z3 = {b0v[3]+tf*cbv[3], b0v[3]+tf*cbv[3], b0v[3]+tf*cbv[3], b0v[3]+tf*cbv[3]};
            #pragma unroll
            for (int kt = 0; kt < 4; ++kt) {
                half8 hf = *reinterpret_cast<const half8*>(&lds[H0r + l15*PH + kt*32 + lg*8]);
                z0 = MFMA16(hf, rk0r[0][kt], z0);
                z1 = MFMA16(hf, rk0r[1][kt], z1);
                z2 = MFMA16(hf, rk0r[2][kt], z2);
                z3 = MFMA16(hf, rk0r[3][kt], z3);
            }
            half8 ax0 = *reinterpret_cast<const half8*>(&lds[A0r + l15*PA0 +  0 + lg*8]);
            half8 ax1 = *reinterpret_cast<const half8*>(&lds[A0r + l15*PA0 + 32 + lg*8]);
            z0 = MFMA16(ax0, wx[0][0], z0); z1 = MFMA16(ax0, wx[1][0], z1);
            z2 = MFMA16(ax0, wx[2][0], z2); z3 = MFMA16(ax0, wx[3][0], z3);
            z0 = MFMA16(ax1, wx[0][1], z0); z1 = MFMA16(ax1, wx[1][1], z1);
            z2 = MFMA16(ax1, wx[2][1], z2); z3 = MFMA16(ax1, wx[3][1], z3);
            half8 aac = { (_Float16)accv[0], (_Float16)accv[1], (_Float16)accv[2], (_Float16)accv[3],
                          (_Float16)accv[4], (_Float16)accv[5], (_Float16)accv[6], (_Float16)accv[7] };
            z0 = MFMA16(aac, w0a[0], z0); z1 = MFMA16(aac, w0a[1], z1);
            z2 = MFMA16(aac, w0a[2], z2); z3 = MFMA16(aac, w0a[3], z3);
            #pragma unroll
            for (int r = 0; r < 4; ++r) {
                float iv = sigm (z0[r]);
                float fv = sigm (z1[r]);
                float gv = tanh_(z2[r]);
                float ov = sigm (z3[r]);
                float cn = fv * c0[r] + iv * gv;
                c0[r] = cn;
                lds[H0w + (lg*4 + r)*PH + colw] = (_Float16)(ov * tanh_(cn));
            }
        }
        bar();  // barA: h0(t) ready

        // ======== seg2: z1 = h0@k1 + h1_prev@rk1 -> h1; stage x(t+1) ========
        {
            {   // stage x(t+1) (published by barB); issue load x(t+2)
                half2v xh = { (_Float16)xr.x, (_Float16)xr.y };
                *reinterpret_cast<half2v*>(&lds[A0w + xrow2*PA0 + xc2]) = xh;
                int tn = t + 2; if (tn > 255) tn = 255;
                xr = *reinterpret_cast<const float2*>(&xin[(size_t)(b0 + xrow2)*16384 + tn*64 + xc2]);
            }
            f32x4 z0 = {b1v[0],b1v[0],b1v[0],b1v[0]};
            f32x4 z1 = {b1v[1],b1v[1],b1v[1],b1v[1]};
            f32x4 z2 = {b1v[2],b1v[2],b1v[2],b1v[2]};
            f32x4 z3 = {b1v[3],b1v[3],b1v[3],b1v[3]};
            #pragma unroll
            for (int kt = 0; kt < 3; ++kt) {
                half8 hf = *reinterpret_cast<const half8*>(&lds[H0w + l15*PH + kt*32 + lg*8]);
                z0 = MFMA16(hf, *reinterpret_cast<const half8*>(&lds[L_K1 + (nt0*3 + kt)*512 + lane*8]), z0);
                z1 = MFMA16(hf, *reinterpret_cast<const half8*>(&lds[L_K1 + (nt1*3 + kt)*512 + lane*8]), z1);
                z2 = MFMA16(hf, *reinterpret_cast<const half8*>(&lds[L_K1 + (nt2*3 + kt)*512 + lane*8]), z2);
                z3 = MFMA16(hf, *reinterpret_cast<const half8*>(&lds[L_K1 + (nt3*3 + kt)*512 + lane*8]), z3);
            }
            {
                half8 hf = *reinterpret_cast<const half8*>(&lds[H0w + l15*PH + 3*32 + lg*8]);
                z0 = MFMA16(hf, k1r[0], z0);
                z1 = MFMA16(hf, k1r[1], z1);
                z2 = MFMA16(hf, k1r[2], z2);
                z3 = MFMA16(hf, k1r[3], z3);
            }
            #pragma unroll
            for (int kt = 0; kt < 4; ++kt) {
                half8 hf = *reinterpret_cast<const half8*>(&lds[H1r + l15*PH + kt*32 + lg*8]);
                z0 = MFMA16(hf, rk1r[0][kt], z0);
                z1 = MFMA16(hf, rk1r[1][kt], z1);
                z2 = MFMA16(hf, rk1r[2][kt], z2);
                z3 = MFMA16(hf, rk1r[3][kt], z3);
            }
            #pragma unroll
            for (int r = 0; r < 4; ++r) {
                float iv = sigm (z0[r]);
                float fv = sigm (z1[r]);
                float gv = tanh_(z2[r]);
                float ov = sigm (z3[r]);
                float cn = fv * c1[r] + iv * gv;
                c1[r] = cn;
                lds[H1w + (lg*4 + r)*PH + colw] = (_Float16)(ov * tanh_(cn));
            }
        }
        bar();  // barB: h1(t) + x(t+1) ready

        // ======== post: GEMM4 (all waves); wave-local transpose; accv; store ========
        {
            f32x4 rr0 = {0.f,0.f,0.f,0.f}, rr1 = {0.f,0.f,0.f,0.f};
            #pragma unroll
            for (int kt = 0; kt < 4; ++kt) {
                half8 hf  = *reinterpret_cast<const half8*>(&lds[H1w + l15*PH + kt*32 + lg*8]);
                half8 wt0 = *reinterpret_cast<const half8*>(&lds[L_WOUT + (0*4 + kt)*512 + lane*8]);
                half8 wt1 = *reinterpret_cast<const half8*>(&lds[L_WOUT + (1*4 + kt)*512 + lane*8]);
                rr0 = MFMA16(wt0, hf, rr0);     // D: [rescol = lg*4+r][batch = l15]
                rr1 = MFMA16(wt1, hf, rr1);
            }
            #pragma unroll
            for (int r = 0; r < 4; ++r) {       // buf[batch][rescol]
                lds[resw - l15*PRES + (lg*4 + r)*0 + l15*PRES + lg*4 + r] = (_Float16)rr0[r];
                lds[resw + 16 + lg*4 + r] = (_Float16)rr1[r];
            }
            asm volatile("s_waitcnt lgkmcnt(0)" ::: "memory");
            half8 resA = *reinterpret_cast<const half8*>(&lds[resw + lg*8]);
            #pragma unroll
            for (int j = 0; j < 8; ++j) accv[j] += (float)resA[j];
            if (W < 2) {
                const f32x4& rrs = (W == 0) ? rr0 : rr1;
                float4 ov = { rrs[0]+boutv4[0], rrs[1]+boutv4[1], rrs[2]+boutv4[2], rrs[3]+boutv4[3] };
                *reinterpret_cast<float4*>(&out[(size_t)(b0 + l15)*8192 + t*32 + W*16 + lg*4]) = ov;
            }
        }
        // no barrier: transpose is wave-local; seg1(t+1) touches disjoint LDS.
    };

    #pragma unroll 1
    for (int t = 0; t < 256; t += 2) {
        step(std::integral_constant<int,0>{}, t);
        step(std::integral_constant<int,1>{}, t + 1);
    }
}

extern "C" void kernel_launch(void* const* d_in, const int* in_sizes, int n_in,
                              void* d_out, int out_size, void* d_ws, size_t ws_size,
                              hipStream_t stream) {
    (void)in_sizes; (void)n_in; (void)out_size; (void)ws_size;
    const float* x     = (const float*)d_in[0];
    const float* W_in  = (const float*)d_in[1];
    const float* b_in  = (const float*)d_in[2];
    const float* k0    = (const float*)d_in[3];
    const float* rk0   = (const float*)d_in[4];
    const float* bb0   = (const float*)d_in[5];
    const float* k1    = (const float*)d_in[6];
    const float* rk1   = (const float*)d_in[7];
    const float* bb1   = (const float*)d_in[8];
    const float* W_out = (const float*)d_in[9];
    const float* b_out = (const float*)d_in[10];
    float* out = (float*)d_out;

    _Float16* ws     = (_Float16*)d_ws;
    _Float16* wl1p   = ws + WS_WL1;
    _Float16* rk0p   = ws + WS_RK0;
    _Float16* w0p    = ws + WS_W0;
    _Float16* woutTp = ws + WS_WOUTT;
    float*    b0p    = (float*)(ws + WS_B0);
    float*    cbp    = (float*)(ws + WS_CB);

    pack_layer_k<<<512, 256, 0, stream>>>(k1, rk1, wl1p);
    pack_rk     <<<256, 256, 0, stream>>>(rk0, rk0p);
    pack_w0     <<<192, 256, 0, stream>>>(W_in, k0, w0p);
    pack_b0     <<<2,   256, 0, stream>>>(b_in, k0, bb0, b0p);
    pack_woutT  <<<16,  256, 0, stream>>>(W_out, woutTp);
    pack_cb     <<<2,   256, 0, stream>>>(W_in, k0, b_out, cbp);
    acclstm_main<<<256, 512, 0, stream>>>(x, wl1p, rk0p, w0p, woutTp,
                                          b0p, cbp, bb1, b_out, out);
}

// Round 9
// 1283.118 us; speedup vs baseline: 1.1182x; 1.1182x over previous
//
#include <hip/hip_runtime.h>
#include <hip/hip_fp16.h>

typedef _Float16 half8  __attribute__((ext_vector_type(8)));
typedef _Float16 half4v __attribute__((ext_vector_type(4)));
typedef _Float16 half2v __attribute__((ext_vector_type(2)));
typedef float    f32x4  __attribute__((ext_vector_type(4)));

#define MFMA16(af, bf, cf) __builtin_amdgcn_mfma_f32_16x16x32_f16((af), (bf), (cf), 0, 0, 0)

// ---------------- workspace layout (halves) ----------------
#define WS_WL1   0                        // [k1;rk1] packed [nt0..31][kt0..7][512] = 131072
#define WS_RK0   131072                   // rk0 packed [nt][kt0..3][512] = 65536
#define WS_W0    (131072 + 65536)         // W0' = W_in@k0 packed [nt][kt0..2][512] = 49152
#define WS_WOUTT (WS_W0 + 49152)          // Wout^T packed [m0..1][kt0..3][512] = 4096
#define WS_B0    (WS_WOUTT + 4096)        // float b0'[512] (1024 halves)

// ---------------- LDS layout (halves) ----------------
#define PA0  72                            // 64 x cols + 8 pad
#define PH   136                           // 128 cols + 8 pad
#define PRES 40                            // 32 res cols + 8 pad (16B-aligned rows)
#define L_A0X  0                           // single-buffered x: [16][72] = 1152
#define L_H0   1152                        // 2 x [16][136] = 4352
#define L_H1   (L_H0 + 4352)               // 5504
#define L_WOUT (L_H1 + 4352)               // 9856: [2m][4kt][512] = 4096
#define L_RES  (L_WOUT + 4096)             // 13952: 8 waves x [16][40] = 5120
#define L_K1   (L_RES + 5120)              // 19072: k1 kt0..2 [nt][3kt][512] = 49152
#define L_TOT  (L_K1 + 49152)              // 68224 halves = 136448 B

__device__ __forceinline__ float sigm(float x) {
    return __builtin_amdgcn_rcpf(1.0f + __builtin_amdgcn_exp2f(-1.442695041f * x));
}
__device__ __forceinline__ float tanh_(float x) {
    return 1.0f - 2.0f * __builtin_amdgcn_rcpf(__builtin_amdgcn_exp2f(2.885390082f * x) + 1.0f);
}
// raw barrier: drain LDS only; global loads/stores stay in flight.
__device__ __forceinline__ void bar() {
    asm volatile("s_waitcnt lgkmcnt(0)" ::: "memory");
    __builtin_amdgcn_s_barrier();
    asm volatile("" ::: "memory");
}

// ---- pack kernels ----
__global__ void pack_layer_k(const float* __restrict__ kk, const float* __restrict__ rk,
                             _Float16* __restrict__ dst)
{
    int idx  = blockIdx.x * 256 + threadIdx.x;
    int j    = idx & 7;
    int lane = (idx >> 3) & 63;
    int fk   = idx >> 9;
    int kt   = fk & 7;
    int nt   = fk >> 3;
    int w = nt >> 3, ln = nt & 7, g = ln >> 1, hh = ln & 1;
    int col = g*128 + w*32 + hh*16 + (lane & 15);
    int row = kt*32 + (lane >> 4)*8 + j;
    float v = (row < 128) ? kk[row*512 + col] : rk[(row - 128)*512 + col];
    dst[idx] = (_Float16)v;
}

__global__ void pack_rk(const float* __restrict__ rk, _Float16* __restrict__ dst)
{
    int idx = blockIdx.x * 256 + threadIdx.x;
    int j = idx & 7, lane = (idx >> 3) & 63, fk = idx >> 9;
    int kt = fk & 3, nt = fk >> 2;
    int w = nt >> 3, ln = nt & 7, g = ln >> 1, hh = ln & 1;
    int col = g*128 + w*32 + hh*16 + (lane & 15);
    int row = kt*32 + (lane >> 4)*8 + j;
    dst[idx] = (_Float16)rk[row*512 + col];
}

__global__ void pack_w0(const float* __restrict__ W_in, const float* __restrict__ k0,
                        _Float16* __restrict__ dst)
{
    int idx = blockIdx.x * 256 + threadIdx.x;
    int j = idx & 7, lane = (idx >> 3) & 63, fk = idx >> 9;
    int kt = fk % 3, nt = fk / 3;
    int w = nt >> 3, ln = nt & 7, g = ln >> 1, hh = ln & 1;
    int col = g*128 + w*32 + hh*16 + (lane & 15);
    int row = kt*32 + (lane >> 4)*8 + j;   // rows 0..63 = x, 64..95 = acc
    float s = 0.f;
    #pragma unroll 4
    for (int k = 0; k < 128; ++k) s += W_in[row*128 + k] * k0[k*512 + col];
    dst[idx] = (_Float16)s;
}

__global__ void pack_b0(const float* __restrict__ b_in, const float* __restrict__ k0,
                        const float* __restrict__ bb0, float* __restrict__ b0p)
{
    int col = blockIdx.x * 256 + threadIdx.x;
    float s = bb0[col];
    #pragma unroll 4
    for (int k = 0; k < 128; ++k) s += b_in[k] * k0[k*512 + col];
    b0p[col] = s;
}

// Wout^T as A-frags: dst[(m*4+kt)*512 + lane*8 + j] = Wout[kt*32+(lane>>4)*8+j][m*16+(lane&15)]
__global__ void pack_woutT(const float* __restrict__ W_out, _Float16* __restrict__ dst)
{
    int idx = blockIdx.x * 256 + threadIdx.x;   // < 4096
    int j = idx & 7, lane = (idx >> 3) & 63, fk = idx >> 9;
    int kt = fk & 3, m = fk >> 2;
    int row = kt*32 + (lane >> 4)*8 + j;
    int col = m*16 + (lane & 15);
    dst[idx] = (_Float16)W_out[row*32 + col];
}

// 8 waves (2/SIMD). Wave W=(w4,hh) owns hidden cols w4*32+hh*16+[0,16).
// 2 barriers/step. acc in fp16 registers (A-frag layout, exact Sum(res) incl
// bout); every wave computes GEMM4 redundantly (swapped operands) and
// transposes res wave-locally. x staged via single-buffered A0X.
__global__ __launch_bounds__(512, 2)
void acclstm_main(const float* __restrict__ xin,
                  const _Float16* __restrict__ wl1p, const _Float16* __restrict__ rk0p,
                  const _Float16* __restrict__ w0p,  const _Float16* __restrict__ woutTp,
                  const float* __restrict__ b0p, const float* __restrict__ bb1,
                  const float* __restrict__ bout, float* __restrict__ out)
{
    __shared__ __align__(16) _Float16 lds[L_TOT];
    const int tid  = threadIdx.x;
    const int W    = tid >> 6;
    const int lane = tid & 63;
    const int w4   = W & 3;
    const int hh   = W >> 2;
    const int l15  = lane & 15;
    const int lg   = lane >> 4;
    const int b0   = blockIdx.x << 4;
    const int colw = w4*32 + hh*16 + l15;
    const int nt0 = w4*8 + 0 + hh, nt1 = w4*8 + 2 + hh, nt2 = w4*8 + 4 + hh, nt3 = w4*8 + 6 + hh;

    // ---- LDS fills ----
    for (int i = tid; i < 6144; i += 512) {       // k1 kt0..2
        int h = i << 3, nt = h / 1536, rem = h % 1536;
        *reinterpret_cast<uint4*>(&lds[L_K1 + h]) =
            *reinterpret_cast<const uint4*>(&wl1p[nt*4096 + rem]);
    }
    *reinterpret_cast<uint4*>(&lds[L_WOUT + (tid << 3)]) =
        *reinterpret_cast<const uint4*>(&woutTp[tid << 3]);
    {   // zero H0[0] and H1[0] completely (272 uint4 each)
        uint4 z; z.x = z.y = z.z = z.w = 0u;
        if (tid < 272) {
            *reinterpret_cast<uint4*>(&lds[L_H0 + (tid << 3)]) = z;
            *reinterpret_cast<uint4*>(&lds[L_H1 + (tid << 3)]) = z;
        }
    }

    // ---- persistent weight fragments ----
    half8 w0r[4][3], rk0r[4][4], rk1r[4][4], k1r[4];
    {
        const int nts[4] = {nt0, nt1, nt2, nt3};
        #pragma unroll
        for (int g = 0; g < 4; ++g) {
            const int nt = nts[g];
            #pragma unroll
            for (int kt = 0; kt < 3; ++kt)
                w0r[g][kt] = *reinterpret_cast<const half8*>(&w0p[(nt*3 + kt)*512 + lane*8]);
            #pragma unroll
            for (int kt = 0; kt < 4; ++kt)
                rk0r[g][kt] = *reinterpret_cast<const half8*>(&rk0p[(nt*4 + kt)*512 + lane*8]);
            #pragma unroll
            for (int kt = 0; kt < 4; ++kt)
                rk1r[g][kt] = *reinterpret_cast<const half8*>(&wl1p[(nt*8 + 4 + kt)*512 + lane*8]);
            k1r[g] = *reinterpret_cast<const half8*>(&wl1p[(nt*8 + 3)*512 + lane*8]);
        }
    }
    float b0v[4], b1v[4];
    #pragma unroll
    for (int g = 0; g < 4; ++g) {
        b0v[g] = b0p[g*128 + colw];
        b1v[g] = bb1[g*128 + colw];
    }

    f32x4 c0 = {0.f,0.f,0.f,0.f}, c1 = {0.f,0.f,0.f,0.f};
    half8 accv = { (_Float16)0, (_Float16)0, (_Float16)0, (_Float16)0,
                   (_Float16)0, (_Float16)0, (_Float16)0, (_Float16)0 };

    const int xrow2 = tid >> 5, xc2 = (tid & 31) << 1;
    const int resw  = L_RES + W*640 + l15*PRES;   // wave-private transpose buffer

    __syncthreads();
    // stage x(0) -> A0X; xr = x(1)
    float2 xr = *reinterpret_cast<const float2*>(&xin[(size_t)(b0 + xrow2)*16384 + xc2]);
    {
        half2v xh = { (_Float16)xr.x, (_Float16)xr.y };
        *reinterpret_cast<half2v*>(&lds[L_A0X + xrow2*PA0 + xc2]) = xh;
    }
    xr = *reinterpret_cast<const float2*>(&xin[(size_t)(b0 + xrow2)*16384 + 64 + xc2]);
    __syncthreads();

    auto step = [&](auto PARc, int t) {
        constexpr int PAR = decltype(PARc)::value;
        constexpr int H0r = L_H0 + PAR*2176,  H0w = L_H0 + (PAR^1)*2176;
        constexpr int H1r = L_H1 + PAR*2176,  H1w = L_H1 + (PAR^1)*2176;

        // ======== seg1: z0 = b0' + x@W0x + acc@W0a + h0_prev@rk0 -> h0 ========
        {
            f32x4 z0 = {b0v[0],b0v[0],b0v[0],b0v[0]};
            f32x4 z1 = {b0v[1],b0v[1],b0v[1],b0v[1]};
            f32x4 z2 = {b0v[2],b0v[2],b0v[2],b0v[2]};
            f32x4 z3 = {b0v[3],b0v[3],b0v[3],b0v[3]};
            #pragma unroll
            for (int kt = 0; kt < 4; ++kt) {
                half8 hf = *reinterpret_cast<const half8*>(&lds[H0r + l15*PH + kt*32 + lg*8]);
                z0 = MFMA16(hf, rk0r[0][kt], z0);
                z1 = MFMA16(hf, rk0r[1][kt], z1);
                z2 = MFMA16(hf, rk0r[2][kt], z2);
                z3 = MFMA16(hf, rk0r[3][kt], z3);
            }
            half8 ax0 = *reinterpret_cast<const half8*>(&lds[L_A0X + l15*PA0 +  0 + lg*8]);
            half8 ax1 = *reinterpret_cast<const half8*>(&lds[L_A0X + l15*PA0 + 32 + lg*8]);
            z0 = MFMA16(ax0, w0r[0][0], z0); z1 = MFMA16(ax0, w0r[1][0], z1);
            z2 = MFMA16(ax0, w0r[2][0], z2); z3 = MFMA16(ax0, w0r[3][0], z3);
            z0 = MFMA16(ax1, w0r[0][1], z0); z1 = MFMA16(ax1, w0r[1][1], z1);
            z2 = MFMA16(ax1, w0r[2][1], z2); z3 = MFMA16(ax1, w0r[3][1], z3);
            z0 = MFMA16(accv, w0r[0][2], z0); z1 = MFMA16(accv, w0r[1][2], z1);
            z2 = MFMA16(accv, w0r[2][2], z2); z3 = MFMA16(accv, w0r[3][2], z3);
            #pragma unroll
            for (int r = 0; r < 4; ++r) {
                float iv = sigm (z0[r]);
                float fv = sigm (z1[r]);
                float gv = tanh_(z2[r]);
                float ov = sigm (z3[r]);
                float cn = fv * c0[r] + iv * gv;
                c0[r] = cn;
                lds[H0w + (lg*4 + r)*PH + colw] = (_Float16)(ov * tanh_(cn));
            }
        }
        bar();  // barA: h0(t) ready; A0X(t) fully consumed

        // ======== seg2: z1 = h0@k1 + h1_prev@rk1 -> h1; stage x(t+1) ========
        {
            {   // stage x(t+1) into A0X (published by barB); prefetch x(t+2)
                half2v xh = { (_Float16)xr.x, (_Float16)xr.y };
                *reinterpret_cast<half2v*>(&lds[L_A0X + xrow2*PA0 + xc2]) = xh;
                int tn = t + 2; if (tn > 255) tn = 255;
                xr = *reinterpret_cast<const float2*>(&xin[(size_t)(b0 + xrow2)*16384 + tn*64 + xc2]);
            }
            f32x4 z0 = {b1v[0],b1v[0],b1v[0],b1v[0]};
            f32x4 z1 = {b1v[1],b1v[1],b1v[1],b1v[1]};
            f32x4 z2 = {b1v[2],b1v[2],b1v[2],b1v[2]};
            f32x4 z3 = {b1v[3],b1v[3],b1v[3],b1v[3]};
            #pragma unroll
            for (int kt = 0; kt < 3; ++kt) {
                half8 hf = *reinterpret_cast<const half8*>(&lds[H0w + l15*PH + kt*32 + lg*8]);
                z0 = MFMA16(hf, *reinterpret_cast<const half8*>(&lds[L_K1 + (nt0*3 + kt)*512 + lane*8]), z0);
                z1 = MFMA16(hf, *reinterpret_cast<const half8*>(&lds[L_K1 + (nt1*3 + kt)*512 + lane*8]), z1);
                z2 = MFMA16(hf, *reinterpret_cast<const half8*>(&lds[L_K1 + (nt2*3 + kt)*512 + lane*8]), z2);
                z3 = MFMA16(hf, *reinterpret_cast<const half8*>(&lds[L_K1 + (nt3*3 + kt)*512 + lane*8]), z3);
            }
            {
                half8 hf = *reinterpret_cast<const half8*>(&lds[H0w + l15*PH + 3*32 + lg*8]);
                z0 = MFMA16(hf, k1r[0], z0);
                z1 = MFMA16(hf, k1r[1], z1);
                z2 = MFMA16(hf, k1r[2], z2);
                z3 = MFMA16(hf, k1r[3], z3);
            }
            #pragma unroll
            for (int kt = 0; kt < 4; ++kt) {
                half8 hf = *reinterpret_cast<const half8*>(&lds[H1r + l15*PH + kt*32 + lg*8]);
                z0 = MFMA16(hf, rk1r[0][kt], z0);
                z1 = MFMA16(hf, rk1r[1][kt], z1);
                z2 = MFMA16(hf, rk1r[2][kt], z2);
                z3 = MFMA16(hf, rk1r[3][kt], z3);
            }
            #pragma unroll
            for (int r = 0; r < 4; ++r) {
                float iv = sigm (z0[r]);
                float fv = sigm (z1[r]);
                float gv = tanh_(z2[r]);
                float ov = sigm (z3[r]);
                float cn = fv * c1[r] + iv * gv;
                c1[r] = cn;
                lds[H1w + (lg*4 + r)*PH + colw] = (_Float16)(ov * tanh_(cn));
            }
        }
        bar();  // barB: h1(t) + x(t+1) ready

        // ======== post: GEMM4 (all waves, bout folded in); transpose; acc; store ========
        {
            float4 bt0 = *reinterpret_cast<const float4*>(&bout[lg*4]);
            float4 bt1 = *reinterpret_cast<const float4*>(&bout[16 + lg*4]);
            f32x4 rr0 = {bt0.x, bt0.y, bt0.z, bt0.w};
            f32x4 rr1 = {bt1.x, bt1.y, bt1.z, bt1.w};
            #pragma unroll
            for (int kt = 0; kt < 4; ++kt) {
                half8 hf  = *reinterpret_cast<const half8*>(&lds[H1w + l15*PH + kt*32 + lg*8]);
                half8 wt0 = *reinterpret_cast<const half8*>(&lds[L_WOUT + (0*4 + kt)*512 + lane*8]);
                half8 wt1 = *reinterpret_cast<const half8*>(&lds[L_WOUT + (1*4 + kt)*512 + lane*8]);
                rr0 = MFMA16(wt0, hf, rr0);     // D: [rescol = lg*4+r][batch = l15]
                rr1 = MFMA16(wt1, hf, rr1);
            }
            if (W < 2) {                        // out-store (fire-and-forget)
                const f32x4& rrs = (W == 0) ? rr0 : rr1;
                float4 ov = { rrs[0], rrs[1], rrs[2], rrs[3] };
                *reinterpret_cast<float4*>(&out[(size_t)(b0 + l15)*8192 + t*32 + W*16 + lg*4]) = ov;
            }
            // wave-local transpose: buf[batch l15][rescol]
            half4v p0 = { (_Float16)rr0[0], (_Float16)rr0[1], (_Float16)rr0[2], (_Float16)rr0[3] };
            half4v p1 = { (_Float16)rr1[0], (_Float16)rr1[1], (_Float16)rr1[2], (_Float16)rr1[3] };
            *reinterpret_cast<half4v*>(&lds[resw + lg*4])      = p0;
            *reinterpret_cast<half4v*>(&lds[resw + 16 + lg*4]) = p1;
            asm volatile("s_waitcnt lgkmcnt(0)" ::: "memory");
            half8 resA = *reinterpret_cast<const half8*>(&lds[resw + lg*8]);
            #pragma unroll
            for (int j = 0; j < 8; ++j)
                accv[j] = (_Float16)((float)accv[j] + (float)resA[j]);
        }
        // no barrier: RES is wave-private; accv is registers.
    };

    #pragma unroll 1
    for (int t = 0; t < 256; t += 2) {
        step(std::integral_constant<int,0>{}, t);
        step(std::integral_constant<int,1>{}, t + 1);
    }
}

extern "C" void kernel_launch(void* const* d_in, const int* in_sizes, int n_in,
                              void* d_out, int out_size, void* d_ws, size_t ws_size,
                              hipStream_t stream) {
    (void)in_sizes; (void)n_in; (void)out_size; (void)ws_size;
    const float* x     = (const float*)d_in[0];
    const float* W_in  = (const float*)d_in[1];
    const float* b_in  = (const float*)d_in[2];
    const float* k0    = (const float*)d_in[3];
    const float* rk0   = (const float*)d_in[4];
    const float* bb0   = (const float*)d_in[5];
    const float* k1    = (const float*)d_in[6];
    const float* rk1   = (const float*)d_in[7];
    const float* bb1   = (const float*)d_in[8];
    const float* W_out = (const float*)d_in[9];
    const float* b_out = (const float*)d_in[10];
    float* out = (float*)d_out;

    _Float16* ws     = (_Float16*)d_ws;
    _Float16* wl1p   = ws + WS_WL1;
    _Float16* rk0p   = ws + WS_RK0;
    _Float16* w0p    = ws + WS_W0;
    _Float16* woutTp = ws + WS_WOUTT;
    float*    b0p    = (float*)(ws + WS_B0);

    pack_layer_k<<<512, 256, 0, stream>>>(k1, rk1, wl1p);
    pack_rk     <<<256, 256, 0, stream>>>(rk0, rk0p);
    pack_w0     <<<192, 256, 0, stream>>>(W_in, k0, w0p);
    pack_b0     <<<2,   256, 0, stream>>>(b_in, k0, bb0, b0p);
    pack_woutT  <<<16,  256, 0, stream>>>(W_out, woutTp);
    acclstm_main<<<256, 512, 0, stream>>>(x, wl1p, rk0p, w0p, woutTp,
                                          b0p, bb1, b_out, out);
}

// Round 11
// 979.347 us; speedup vs baseline: 1.4651x; 1.3102x over previous
//
#include <hip/hip_runtime.h>
#include <hip/hip_fp16.h>

typedef _Float16 half8  __attribute__((ext_vector_type(8)));
typedef _Float16 half2v __attribute__((ext_vector_type(2)));
typedef float    f32x4  __attribute__((ext_vector_type(4)));
typedef int      int4v  __attribute__((ext_vector_type(4)));

#define MFMA16(af, bf, cf) __builtin_amdgcn_mfma_f32_16x16x32_f16((af), (bf), (cf), 0, 0, 0)

// ---------------- workspace layout (halves) ----------------
#define WS_WL1   0                        // [k1;rk1] packed [nt0..31][kt0..7][512] = 131072
#define WS_RK0   131072                   // rk0 packed [nt][kt0..3][512] = 65536
#define WS_W0    (131072 + 65536)         // W0' = W_in@k0 packed [nt][kt0..2][512] = 49152
#define WS_WOUTT (WS_W0 + 49152)          // Wout^T packed [m0..1][kt0..3][512] = 4096
#define WS_B0    (WS_WOUTT + 4096)        // float b0'[512] (1024 halves)

// ---------------- LDS layout (halves) ----------------
#define PA0  72                            // 64 x cols + 8 pad
#define PH   136                           // 128 cols + 8 pad
#define L_A0X  0                           // single-buffered x: [16][72] = 1152
#define L_H0   1152                        // 2 x [16][136] = 4352
#define L_H1   (L_H0 + 4352)               // 5504: 2 x [16][136]
#define L_WOUT (L_H1 + 4352)               // 9856: [2m][4kt][512] = 4096
#define L_K1   (L_WOUT + 4096)             // 13952: k1 kt0..3 [nt][kt][512] = 65536
#define L_TOT  (L_K1 + 65536)              // 79488 halves = 158976 B
// No LDS transpose scratch: res D-layout -> A-frag layout is done with
// ds_bpermute (register permute, no storage, no aliasing possible).
// R10 lesson: "dead buffer" reuse overflowed H1[PAR] (2176 halves) into the
// LIVE H1[PAR^1] -- waves 4..7 corrupted h1(t). Never again without a
// byte-exact footprint proof against the SINGLE parity buffer.

__device__ __forceinline__ float sigm(float x) {
    return __builtin_amdgcn_rcpf(1.0f + __builtin_amdgcn_exp2f(-1.442695041f * x));
}
__device__ __forceinline__ float tanh_(float x) {
    return 1.0f - 2.0f * __builtin_amdgcn_rcpf(__builtin_amdgcn_exp2f(2.885390082f * x) + 1.0f);
}
// raw barrier: drain LDS only; global loads/stores stay in flight.
__device__ __forceinline__ void bar() {
    asm volatile("s_waitcnt lgkmcnt(0)" ::: "memory");
    __builtin_amdgcn_s_barrier();
    asm volatile("" ::: "memory");
}

// ---- pack kernels ----
__global__ void pack_layer_k(const float* __restrict__ kk, const float* __restrict__ rk,
                             _Float16* __restrict__ dst)
{
    int idx  = blockIdx.x * 256 + threadIdx.x;
    int j    = idx & 7;
    int lane = (idx >> 3) & 63;
    int fk   = idx >> 9;
    int kt   = fk & 7;
    int nt   = fk >> 3;
    int w = nt >> 3, ln = nt & 7, g = ln >> 1, hh = ln & 1;
    int col = g*128 + w*32 + hh*16 + (lane & 15);
    int row = kt*32 + (lane >> 4)*8 + j;
    float v = (row < 128) ? kk[row*512 + col] : rk[(row - 128)*512 + col];
    dst[idx] = (_Float16)v;
}

__global__ void pack_rk(const float* __restrict__ rk, _Float16* __restrict__ dst)
{
    int idx = blockIdx.x * 256 + threadIdx.x;
    int j = idx & 7, lane = (idx >> 3) & 63, fk = idx >> 9;
    int kt = fk & 3, nt = fk >> 2;
    int w = nt >> 3, ln = nt & 7, g = ln >> 1, hh = ln & 1;
    int col = g*128 + w*32 + hh*16 + (lane & 15);
    int row = kt*32 + (lane >> 4)*8 + j;
    dst[idx] = (_Float16)rk[row*512 + col];
}

__global__ void pack_w0(const float* __restrict__ W_in, const float* __restrict__ k0,
                        _Float16* __restrict__ dst)
{
    int idx = blockIdx.x * 256 + threadIdx.x;
    int j = idx & 7, lane = (idx >> 3) & 63, fk = idx >> 9;
    int kt = fk % 3, nt = fk / 3;
    int w = nt >> 3, ln = nt & 7, g = ln >> 1, hh = ln & 1;
    int col = g*128 + w*32 + hh*16 + (lane & 15);
    int row = kt*32 + (lane >> 4)*8 + j;   // rows 0..63 = x, 64..95 = acc
    float s = 0.f;
    #pragma unroll 4
    for (int k = 0; k < 128; ++k) s += W_in[row*128 + k] * k0[k*512 + col];
    dst[idx] = (_Float16)s;
}

__global__ void pack_b0(const float* __restrict__ b_in, const float* __restrict__ k0,
                        const float* __restrict__ bb0, float* __restrict__ b0p)
{
    int col = blockIdx.x * 256 + threadIdx.x;
    float s = bb0[col];
    #pragma unroll 4
    for (int k = 0; k < 128; ++k) s += b_in[k] * k0[k*512 + col];
    b0p[col] = s;
}

// Wout^T as A-frags: dst[(m*4+kt)*512 + lane*8 + j] = Wout[kt*32+(lane>>4)*8+j][m*16+(lane&15)]
__global__ void pack_woutT(const float* __restrict__ W_out, _Float16* __restrict__ dst)
{
    int idx = blockIdx.x * 256 + threadIdx.x;   // < 4096
    int j = idx & 7, lane = (idx >> 3) & 63, fk = idx >> 9;
    int kt = fk & 3, m = fk >> 2;
    int row = kt*32 + (lane >> 4)*8 + j;
    int col = m*16 + (lane & 15);
    dst[idx] = (_Float16)W_out[row*32 + col];
}

// 8 waves (2/SIMD). Wave W=(w4,hh) owns hidden cols w4*32+hh*16+[0,16).
// 2 barriers/step. acc in fp16 regs (A-frag layout, = Sum(res) incl bout);
// all waves compute GEMM4 redundantly (swapped operands); res D-layout ->
// A-frag via 8x ds_bpermute (register permute, raceless). x via A0X.
__global__ __launch_bounds__(512, 2)
void acclstm_main(const float* __restrict__ xin,
                  const _Float16* __restrict__ wl1p, const _Float16* __restrict__ rk0p,
                  const _Float16* __restrict__ w0p,  const _Float16* __restrict__ woutTp,
                  const float* __restrict__ b0p, const float* __restrict__ bb1,
                  const float* __restrict__ bout, float* __restrict__ out)
{
    __shared__ __align__(16) _Float16 lds[L_TOT];
    const int tid  = threadIdx.x;
    const int W    = tid >> 6;
    const int lane = tid & 63;
    const int w4   = W & 3;
    const int hh   = W >> 2;
    const int l15  = lane & 15;
    const int lg   = lane >> 4;
    const int b0   = blockIdx.x << 4;
    const int colw = w4*32 + hh*16 + l15;
    const int nt0 = w4*8 + 0 + hh, nt1 = w4*8 + 2 + hh, nt2 = w4*8 + 4 + hh, nt3 = w4*8 + 6 + hh;
    // bpermute byte-indices for res transpose: srcLane = (lg&1)*32 + l15 (+16)
    const int idxA = (((lg & 1) << 5) + l15) << 2;
    const int idxB = idxA + 64;

    // ---- LDS fills ----
    for (int i = tid; i < 8192; i += 512) {       // k1 kt0..3 (full)
        int h = i << 3, nt = h >> 11, rem = h & 2047;
        *reinterpret_cast<uint4*>(&lds[L_K1 + h]) =
            *reinterpret_cast<const uint4*>(&wl1p[nt*4096 + rem]);
    }
    *reinterpret_cast<uint4*>(&lds[L_WOUT + (tid << 3)]) =
        *reinterpret_cast<const uint4*>(&woutTp[tid << 3]);
    {   // zero H0[0] and H1[0] completely (272 uint4 each)
        uint4 z; z.x = z.y = z.z = z.w = 0u;
        if (tid < 272) {
            *reinterpret_cast<uint4*>(&lds[L_H0 + (tid << 3)]) = z;
            *reinterpret_cast<uint4*>(&lds[L_H1 + (tid << 3)]) = z;
        }
    }

    // ---- persistent weight fragments (176 VGPR) ----
    half8 w0r[4][3], rk0r[4][4], rk1r[4][4];
    {
        const int nts[4] = {nt0, nt1, nt2, nt3};
        #pragma unroll
        for (int g = 0; g < 4; ++g) {
            const int nt = nts[g];
            #pragma unroll
            for (int kt = 0; kt < 3; ++kt)
                w0r[g][kt] = *reinterpret_cast<const half8*>(&w0p[(nt*3 + kt)*512 + lane*8]);
            #pragma unroll
            for (int kt = 0; kt < 4; ++kt)
                rk0r[g][kt] = *reinterpret_cast<const half8*>(&rk0p[(nt*4 + kt)*512 + lane*8]);
            #pragma unroll
            for (int kt = 0; kt < 4; ++kt)
                rk1r[g][kt] = *reinterpret_cast<const half8*>(&wl1p[(nt*8 + 4 + kt)*512 + lane*8]);
        }
    }
    float b0v[4], b1v[4];
    #pragma unroll
    for (int g = 0; g < 4; ++g) {
        b0v[g] = b0p[g*128 + colw];
        b1v[g] = bb1[g*128 + colw];
    }

    f32x4 c0 = {0.f,0.f,0.f,0.f}, c1 = {0.f,0.f,0.f,0.f};
    half8 accv = { (_Float16)0, (_Float16)0, (_Float16)0, (_Float16)0,
                   (_Float16)0, (_Float16)0, (_Float16)0, (_Float16)0 };

    const int xrow2 = tid >> 5, xc2 = (tid & 31) << 1;

    __syncthreads();
    // stage x(0) -> A0X; xr = x(1)
    float2 xr = *reinterpret_cast<const float2*>(&xin[(size_t)(b0 + xrow2)*16384 + xc2]);
    {
        half2v xh = { (_Float16)xr.x, (_Float16)xr.y };
        *reinterpret_cast<half2v*>(&lds[L_A0X + xrow2*PA0 + xc2]) = xh;
    }
    xr = *reinterpret_cast<const float2*>(&xin[(size_t)(b0 + xrow2)*16384 + 64 + xc2]);
    __syncthreads();

    auto step = [&](auto PARc, int t) {
        constexpr int PAR = decltype(PARc)::value;
        constexpr int H0r = L_H0 + PAR*2176,  H0w = L_H0 + (PAR^1)*2176;
        constexpr int H1r = L_H1 + PAR*2176,  H1w = L_H1 + (PAR^1)*2176;

        // ======== seg1: z0 = b0' + x@W0x + acc@W0a + h0_prev@rk0 -> h0 ========
        {
            f32x4 z0 = {b0v[0],b0v[0],b0v[0],b0v[0]};
            f32x4 z1 = {b0v[1],b0v[1],b0v[1],b0v[1]};
            f32x4 z2 = {b0v[2],b0v[2],b0v[2],b0v[2]};
            f32x4 z3 = {b0v[3],b0v[3],b0v[3],b0v[3]};
            #pragma unroll
            for (int kt = 0; kt < 4; ++kt) {
                half8 hf = *reinterpret_cast<const half8*>(&lds[H0r + l15*PH + kt*32 + lg*8]);
                z0 = MFMA16(hf, rk0r[0][kt], z0);
                z1 = MFMA16(hf, rk0r[1][kt], z1);
                z2 = MFMA16(hf, rk0r[2][kt], z2);
                z3 = MFMA16(hf, rk0r[3][kt], z3);
            }
            half8 ax0 = *reinterpret_cast<const half8*>(&lds[L_A0X + l15*PA0 +  0 + lg*8]);
            half8 ax1 = *reinterpret_cast<const half8*>(&lds[L_A0X + l15*PA0 + 32 + lg*8]);
            z0 = MFMA16(ax0, w0r[0][0], z0); z1 = MFMA16(ax0, w0r[1][0], z1);
            z2 = MFMA16(ax0, w0r[2][0], z2); z3 = MFMA16(ax0, w0r[3][0], z3);
            z0 = MFMA16(ax1, w0r[0][1], z0); z1 = MFMA16(ax1, w0r[1][1], z1);
            z2 = MFMA16(ax1, w0r[2][1], z2); z3 = MFMA16(ax1, w0r[3][1], z3);
            z0 = MFMA16(accv, w0r[0][2], z0); z1 = MFMA16(accv, w0r[1][2], z1);
            z2 = MFMA16(accv, w0r[2][2], z2); z3 = MFMA16(accv, w0r[3][2], z3);
            #pragma unroll
            for (int r = 0; r < 4; ++r) {
                float iv = sigm (z0[r]);
                float fv = sigm (z1[r]);
                float gv = tanh_(z2[r]);
                float ov = sigm (z3[r]);
                float cn = fv * c0[r] + iv * gv;
                c0[r] = cn;
                lds[H0w + (lg*4 + r)*PH + colw] = (_Float16)(ov * tanh_(cn));
            }
        }
        bar();  // barA: h0(t) ready; A0X(t) fully consumed

        // ======== seg2: z1 = h0@k1(LDS) + h1_prev@rk1 -> h1; stage x(t+1) ========
        {
            {   // stage x(t+1) into A0X (published by barB); prefetch x(t+2)
                half2v xh = { (_Float16)xr.x, (_Float16)xr.y };
                *reinterpret_cast<half2v*>(&lds[L_A0X + xrow2*PA0 + xc2]) = xh;
                int tn = t + 2; if (tn > 255) tn = 255;
                xr = *reinterpret_cast<const float2*>(&xin[(size_t)(b0 + xrow2)*16384 + tn*64 + xc2]);
            }
            f32x4 z0 = {b1v[0],b1v[0],b1v[0],b1v[0]};
            f32x4 z1 = {b1v[1],b1v[1],b1v[1],b1v[1]};
            f32x4 z2 = {b1v[2],b1v[2],b1v[2],b1v[2]};
            f32x4 z3 = {b1v[3],b1v[3],b1v[3],b1v[3]};
            #pragma unroll
            for (int kt = 0; kt < 4; ++kt) {
                half8 hf = *reinterpret_cast<const half8*>(&lds[H0w + l15*PH + kt*32 + lg*8]);
                z0 = MFMA16(hf, *reinterpret_cast<const half8*>(&lds[L_K1 + (nt0*4 + kt)*512 + lane*8]), z0);
                z1 = MFMA16(hf, *reinterpret_cast<const half8*>(&lds[L_K1 + (nt1*4 + kt)*512 + lane*8]), z1);
                z2 = MFMA16(hf, *reinterpret_cast<const half8*>(&lds[L_K1 + (nt2*4 + kt)*512 + lane*8]), z2);
                z3 = MFMA16(hf, *reinterpret_cast<const half8*>(&lds[L_K1 + (nt3*4 + kt)*512 + lane*8]), z3);
            }
            #pragma unroll
            for (int kt = 0; kt < 4; ++kt) {
                half8 hf = *reinterpret_cast<const half8*>(&lds[H1r + l15*PH + kt*32 + lg*8]);
                z0 = MFMA16(hf, rk1r[0][kt], z0);
                z1 = MFMA16(hf, rk1r[1][kt], z1);
                z2 = MFMA16(hf, rk1r[2][kt], z2);
                z3 = MFMA16(hf, rk1r[3][kt], z3);
            }
            #pragma unroll
            for (int r = 0; r < 4; ++r) {
                float iv = sigm (z0[r]);
                float fv = sigm (z1[r]);
                float gv = tanh_(z2[r]);
                float ov = sigm (z3[r]);
                float cn = fv * c1[r] + iv * gv;
                c1[r] = cn;
                lds[H1w + (lg*4 + r)*PH + colw] = (_Float16)(ov * tanh_(cn));
            }
        }
        bar();  // barB: h1(t) + x(t+1) ready

        // ======== post: GEMM4 (all waves, bout folded); bpermute transpose; acc; store ========
        {
            float4 bt0 = *reinterpret_cast<const float4*>(&bout[lg*4]);
            float4 bt1 = *reinterpret_cast<const float4*>(&bout[16 + lg*4]);
            f32x4 rr0 = {bt0.x, bt0.y, bt0.z, bt0.w};
            f32x4 rr1 = {bt1.x, bt1.y, bt1.z, bt1.w};
            #pragma unroll
            for (int kt = 0; kt < 4; ++kt) {
                half8 hf  = *reinterpret_cast<const half8*>(&lds[H1w + l15*PH + kt*32 + lg*8]);
                half8 wt0 = *reinterpret_cast<const half8*>(&lds[L_WOUT + (0*4 + kt)*512 + lane*8]);
                half8 wt1 = *reinterpret_cast<const half8*>(&lds[L_WOUT + (1*4 + kt)*512 + lane*8]);
                rr0 = MFMA16(wt0, hf, rr0);     // D: [rescol = lg*4+r][batch = l15]
                rr1 = MFMA16(wt1, hf, rr1);
            }
            if (W < 2) {                        // out-store (fire-and-forget)
                const f32x4& rrs = (W == 0) ? rr0 : rr1;
                float4 ov = { rrs[0], rrs[1], rrs[2], rrs[3] };
                *reinterpret_cast<float4*>(&out[(size_t)(b0 + l15)*8192 + t*32 + W*16 + lg*4]) = ov;
            }
            // D-layout -> A-frag via ds_bpermute (no LDS storage, raceless).
            half2v h00 = { (_Float16)rr0[0], (_Float16)rr0[1] };
            half2v h10 = { (_Float16)rr0[2], (_Float16)rr0[3] };
            half2v h01 = { (_Float16)rr1[0], (_Float16)rr1[1] };
            half2v h11 = { (_Float16)rr1[2], (_Float16)rr1[3] };
            int q00 = __builtin_bit_cast(int, h00);
            int q10 = __builtin_bit_cast(int, h10);
            int q01 = __builtin_bit_cast(int, h01);
            int q11 = __builtin_bit_cast(int, h11);
            int a0 = __builtin_amdgcn_ds_bpermute(idxA, q00);
            int a1 = __builtin_amdgcn_ds_bpermute(idxA, q01);
            int b1_ = __builtin_amdgcn_ds_bpermute(idxA, q10);
            int b2 = __builtin_amdgcn_ds_bpermute(idxA, q11);
            int c2 = __builtin_amdgcn_ds_bpermute(idxB, q00);
            int c3 = __builtin_amdgcn_ds_bpermute(idxB, q01);
            int d2 = __builtin_amdgcn_ds_bpermute(idxB, q10);
            int d3 = __builtin_amdgcn_ds_bpermute(idxB, q11);
            int4v di;
            di[0] = (lg < 2) ? a0 : a1;     // cols lg*8+0,1
            di[1] = (lg < 2) ? b1_ : b2;    // cols lg*8+2,3
            di[2] = (lg < 2) ? c2 : c3;     // cols lg*8+4,5
            di[3] = (lg < 2) ? d2 : d3;     // cols lg*8+6,7
            half8 resA = __builtin_bit_cast(half8, di);
            #pragma unroll
            for (int j = 0; j < 8; ++j)
                accv[j] = (_Float16)((float)accv[j] + (float)resA[j]);
        }
        // no barrier: post touches no shared LDS state that is re-written
        // before barA(t+1)/barB(t+1).
    };

    #pragma unroll 1
    for (int t = 0; t < 256; t += 2) {
        step(std::integral_constant<int,0>{}, t);
        step(std::integral_constant<int,1>{}, t + 1);
    }
}

extern "C" void kernel_launch(void* const* d_in, const int* in_sizes, int n_in,
                              void* d_out, int out_size, void* d_ws, size_t ws_size,
                              hipStream_t stream) {
    (void)in_sizes; (void)n_in; (void)out_size; (void)ws_size;
    const float* x     = (const float*)d_in[0];
    const float* W_in  = (const float*)d_in[1];
    const float* b_in  = (const float*)d_in[2];
    const float* k0    = (const float*)d_in[3];
    const float* rk0   = (const float*)d_in[4];
    const float* bb0   = (const float*)d_in[5];
    const float* k1    = (const float*)d_in[6];
    const float* rk1   = (const float*)d_in[7];
    const float* bb1   = (const float*)d_in[8];
    const float* W_out = (const float*)d_in[9];
    const float* b_out = (const float*)d_in[10];
    float* out = (float*)d_out;

    _Float16* ws     = (_Float16*)d_ws;
    _Float16* wl1p   = ws + WS_WL1;
    _Float16* rk0p   = ws + WS_RK0;
    _Float16* w0p    = ws + WS_W0;
    _Float16* woutTp = ws + WS_WOUTT;
    float*    b0p    = (float*)(ws + WS_B0);

    pack_layer_k<<<512, 256, 0, stream>>>(k1, rk1, wl1p);
    pack_rk     <<<256, 256, 0, stream>>>(rk0, rk0p);
    pack_w0     <<<192, 256, 0, stream>>>(W_in, k0, w0p);
    pack_b0     <<<2,   256, 0, stream>>>(b_in, k0, bb0, b0p);
    pack_woutT  <<<16,  256, 0, stream>>>(W_out, woutTp);
    acclstm_main<<<256, 512, 0, stream>>>(x, wl1p, rk0p, w0p, woutTp,
                                          b0p, bb1, b_out, out);
}